// Round 4
// baseline (69.391 us; speedup 1.0000x reference)
//
#include <hip/hip_runtime.h>
#include <math.h>

#define NHEADS 4
#define HDIM   32
#define DMODEL 128
#define SLEN   8192
#define BATCH  8
#define QKVC   384   // 3 * NHEADS * HDIM

typedef __bf16 bf16x8 __attribute__((ext_vector_type(8)));
typedef float  f32x4  __attribute__((ext_vector_type(4)));

// round-to-nearest-even f32 -> bf16 bits
static __device__ __forceinline__ unsigned short f2bf(float f) {
    union { float f; unsigned int u; } v; v.f = f;
    unsigned int r = (v.u + 0x7FFFu + ((v.u >> 16) & 1u)) >> 16;
    return (unsigned short)r;
}
static __device__ __forceinline__ unsigned int pack2(float a, float b) {
    return (unsigned int)f2bf(a) | ((unsigned int)f2bf(b) << 16);
}
static __device__ __forceinline__ float bf_lo(unsigned int u) {
    union { unsigned int u; float f; } v; v.u = u << 16; return v.f;
}
static __device__ __forceinline__ float bf_hi(unsigned int u) {
    union { unsigned int u; float f; } v; v.u = u & 0xffff0000u; return v.f;
}

// ---------------------------------------------------------------------------
// Kernel W1: precompute W_qkv MFMA A-fragments (bf16) in fragment order.
//   wfb[(((wave*6+j)*4+ks)*64+lane)*8 + e] =
//       bf16( Wqkv[(ks*32 + (lane>>4)*8 + e) * 384 + wave*96 + j*16 + (lane&15)] )
// 6144 uint4 entries total; grid 24 x 256.
// ---------------------------------------------------------------------------
__global__ __launch_bounds__(256) void k_conv_wqkv(
    const float* __restrict__ Wqkv, unsigned short* __restrict__ wfb)
{
    const int idx  = blockIdx.x * 256 + threadIdx.x;   // 0..6143
    const int lane = idx & 63;
    const int ks   = (idx >> 6) & 3;
    const int rest = idx >> 8;                         // 0..23
    const int j    = rest % 6;
    const int w    = rest / 6;
    const int ch   = w * 96 + j * 16 + (lane & 15);
    const int kb   = ks * 32 + (lane >> 4) * 8;
    unsigned short t[8];
    #pragma unroll
    for (int e = 0; e < 8; ++e) t[e] = f2bf(Wqkv[(kb + e) * QKVC + ch]);
    *(uint4*)(wfb + (long)idx * 8) = *(const uint4*)t;
}

// ---------------------------------------------------------------------------
// Kernel W2: convert + transpose W_out (f32 [8192][128]) -> Wt bf16 [128][8192]
// ---------------------------------------------------------------------------
__global__ __launch_bounds__(256) void k_conv_wout(
    const float* __restrict__ Wout, unsigned short* __restrict__ Wt)
{
    __shared__ unsigned short ts[128][136];
    const int tid = threadIdx.x;
    const int kb  = blockIdx.x;
    const float* src = Wout + (long)kb * 128 * 128;

    #pragma unroll
    for (int i = 0; i < 64; ++i) {
        const int idx = tid + i * 256;
        const int kk = idx >> 7, n = idx & 127;
        ts[n][kk] = f2bf(src[idx]);
    }
    __syncthreads();
    #pragma unroll
    for (int i = 0; i < 64; ++i) {
        const int idx = tid + i * 256;
        const int n = idx >> 7, kk = idx & 127;
        Wt[(long)n * SLEN + kb * 128 + kk] = ts[n][kk];
    }
}

// ---------------------------------------------------------------------------
// Kernel 1: fused QKV projection + per-position head-mixing attention.
// 512 blocks x 256 thr; 4 iters x 32 positions per block.
// MFMA computes qkv^T (W as A-operand, x as B-operand) so each lane owns 4
// consecutive CHANNELS -> packed b64 bf16 writes into swizzled row-major qs.
// Epilogue (waves 0,1): per-(p,qh) softmax with vectorized b128 reads.
// Waves 2,3 overlap next-tile x staging (regs prefetched during MFMA).
// ---------------------------------------------------------------------------
__global__ __launch_bounds__(256, 2) void k_qkv_attn_mfma(
    const float* __restrict__ x,
    const unsigned short* __restrict__ wfb,
    const float* __restrict__ bqkv,
    unsigned short* __restrict__ attn_out)   // bf16 [65536][128]
{
    __shared__ unsigned short xs[32 * 136];   // x tile bf16
    __shared__ unsigned short qsm[32 * 384];  // qkv bf16, chunk-swizzled rows
    __shared__ unsigned short os[32 * 136];   // output staging bf16

    const int tid  = threadIdx.x;
    const int lane = tid & 63;
    const int wave = tid >> 6;
    const int l16  = lane & 15;
    const int lhi  = lane >> 4;

    // --- W fragments (coalesced uint4 loads from precomputed buffer)
    bf16x8 wf[6][4];
    #pragma unroll
    for (int j = 0; j < 6; ++j)
        #pragma unroll
        for (int ks = 0; ks < 4; ++ks)
            wf[j][ks] = __builtin_bit_cast(bf16x8,
                *(const uint4*)(wfb + ((long)(((wave * 6 + j) * 4 + ks) * 64 + lane)) * 8));
    float bq[6][4];
    #pragma unroll
    for (int j = 0; j < 6; ++j)
        #pragma unroll
        for (int r = 0; r < 4; ++r)
            bq[j][r] = bqkv[wave * 96 + j * 16 + lhi * 4 + r];

    const int spos = tid >> 3;   // 0..31  (staging: 16 f32 per thread)
    const int sseg = tid & 7;    // 0..7
    const long p0  = (long)blockIdx.x * 128;

    float4 xv[4];
    // prologue: load + stage iter 0
    {
        const float* src = x + (p0 + spos) * DMODEL + sseg * 16;
        #pragma unroll
        for (int i = 0; i < 4; ++i) xv[i] = *(const float4*)(src + i * 4);
        unsigned short t[16];
        #pragma unroll
        for (int i = 0; i < 4; ++i) {
            t[i * 4 + 0] = f2bf(xv[i].x); t[i * 4 + 1] = f2bf(xv[i].y);
            t[i * 4 + 2] = f2bf(xv[i].z); t[i * 4 + 3] = f2bf(xv[i].w);
        }
        *(uint4*)(xs + spos * 136 + sseg * 16)     = ((const uint4*)t)[0];
        *(uint4*)(xs + spos * 136 + sseg * 16 + 8) = ((const uint4*)t)[1];
    }

    for (int it = 0; it < 4; ++it) {
        __syncthreads();   // xs(it) ready; os(it-1) ready; qs free
        const long pit = p0 + it * 32;

        // store previous iter's output (overlaps MFMA phase)
        if (it > 0) {
            const long pprev = pit - 32;
            #pragma unroll
            for (int i = 0; i < 2; ++i) {
                const int idx = tid + i * 256;
                const int r = idx >> 4, c = idx & 15;
                *(uint4*)(attn_out + (pprev + r) * DMODEL + c * 8) =
                    *(const uint4*)(os + r * 136 + c * 8);
            }
        }

        // MFMA: qkv^T — rows = channels, cols = positions
        {
            f32x4 acc[6][2];
            #pragma unroll
            for (int j = 0; j < 6; ++j)
                #pragma unroll
                for (int nt = 0; nt < 2; ++nt) acc[j][nt] = (f32x4){0.f, 0.f, 0.f, 0.f};

            #pragma unroll
            for (int ks = 0; ks < 4; ++ks) {
                const bf16x8 xf0 = __builtin_bit_cast(bf16x8,
                    *(const uint4*)(xs + l16 * 136 + ks * 32 + lhi * 8));
                const bf16x8 xf1 = __builtin_bit_cast(bf16x8,
                    *(const uint4*)(xs + (16 + l16) * 136 + ks * 32 + lhi * 8));
                #pragma unroll
                for (int j = 0; j < 6; ++j) {
                    acc[j][0] = __builtin_amdgcn_mfma_f32_16x16x32_bf16(wf[j][ks], xf0, acc[j][0], 0, 0, 0);
                    acc[j][1] = __builtin_amdgcn_mfma_f32_16x16x32_bf16(wf[j][ks], xf1, acc[j][1], 0, 0, 0);
                }
            }

            // prefetch next x tile into regs (latency hidden under epilogue)
            if (it < 3) {
                const float* src = x + (pit + 32 + spos) * DMODEL + sseg * 16;
                #pragma unroll
                for (int i = 0; i < 4; ++i) xv[i] = *(const float4*)(src + i * 4);
            }

            // acc -> qs: packed b64 bf16 writes, chunk-swizzled
            const int cb = wave * 96 + lhi * 4;
            #pragma unroll
            for (int j = 0; j < 6; ++j) {
                const int c     = cb + j * 16;
                const int chunk = c >> 3;
                const int sub   = c & 7;          // 0 or 4
                #pragma unroll
                for (int nt = 0; nt < 2; ++nt) {
                    const int p = nt * 16 + l16;
                    uint2 u;
                    u.x = pack2(acc[j][nt][0] + bq[j][0], acc[j][nt][1] + bq[j][1]);
                    u.y = pack2(acc[j][nt][2] + bq[j][2], acc[j][nt][3] + bq[j][3]);
                    *(uint2*)(qsm + p * 384 + ((chunk ^ (p & 7)) << 3) + sub) = u;
                }
            }
        }
        __syncthreads();   // qs ready; xs consumed

        // epilogue: waves 0,1 — thread (p = tid&31, qh = tid>>5)
        if (tid < 128) {
            const int p   = tid & 31;
            const int qh  = tid >> 5;
            const int psw = p & 7;
            const unsigned short* row = qsm + p * 384;
            const float scale = 0.17677669529663687f;   // 32^-0.5

            // q: 4 chunks -> 32 f32
            float qv[32];
            #pragma unroll
            for (int c4 = 0; c4 < 4; ++c4) {
                const uint4 qc = *(const uint4*)(row + (((qh * 12 + c4) ^ psw) << 3));
                const unsigned int* w = (const unsigned int*)&qc;
                #pragma unroll
                for (int k = 0; k < 4; ++k) {
                    qv[c4 * 8 + 2 * k]     = bf_lo(w[k]);
                    qv[c4 * 8 + 2 * k + 1] = bf_hi(w[k]);
                }
            }
            // scores
            float sc[NHEADS];
            #pragma unroll
            for (int kh = 0; kh < NHEADS; ++kh) {
                float s0 = 0.f, s1 = 0.f;
                #pragma unroll
                for (int c4 = 0; c4 < 4; ++c4) {
                    const uint4 kc = *(const uint4*)(row + (((kh * 12 + 4 + c4) ^ psw) << 3));
                    const unsigned int* w = (const unsigned int*)&kc;
                    #pragma unroll
                    for (int k = 0; k < 4; ++k) {
                        s0 = fmaf(bf_lo(w[k]), qv[c4 * 8 + 2 * k], s0);
                        s1 = fmaf(bf_hi(w[k]), qv[c4 * 8 + 2 * k + 1], s1);
                    }
                }
                sc[kh] = (s0 + s1) * scale;
            }
            const float m = fmaxf(fmaxf(sc[0], sc[1]), fmaxf(sc[2], sc[3]));
            float e[NHEADS], sum = 0.f;
            #pragma unroll
            for (int kh = 0; kh < NHEADS; ++kh) { e[kh] = __expf(sc[kh] - m); sum += e[kh]; }
            const float inv = 1.f / sum;

            // PV
            float o[32];
            #pragma unroll
            for (int d = 0; d < 32; ++d) o[d] = 0.f;
            #pragma unroll
            for (int kh = 0; kh < NHEADS; ++kh) {
                const float wk = e[kh] * inv;
                #pragma unroll
                for (int c4 = 0; c4 < 4; ++c4) {
                    const uint4 vc = *(const uint4*)(row + (((kh * 12 + 8 + c4) ^ psw) << 3));
                    const unsigned int* w = (const unsigned int*)&vc;
                    #pragma unroll
                    for (int k = 0; k < 4; ++k) {
                        o[c4 * 8 + 2 * k]     = fmaf(wk, bf_lo(w[k]), o[c4 * 8 + 2 * k]);
                        o[c4 * 8 + 2 * k + 1] = fmaf(wk, bf_hi(w[k]), o[c4 * 8 + 2 * k + 1]);
                    }
                }
            }
            // pack + write os
            unsigned int ow[16];
            #pragma unroll
            for (int j = 0; j < 16; ++j) ow[j] = pack2(o[2 * j], o[2 * j + 1]);
            #pragma unroll
            for (int i = 0; i < 4; ++i)
                *(uint4*)(os + p * 136 + qh * 32 + i * 8) = ((const uint4*)ow)[i];
        }

        // stage next x tile (waves 2,3 start immediately; 0,1 after epilogue)
        if (it < 3) {
            unsigned short t[16];
            #pragma unroll
            for (int i = 0; i < 4; ++i) {
                t[i * 4 + 0] = f2bf(xv[i].x); t[i * 4 + 1] = f2bf(xv[i].y);
                t[i * 4 + 2] = f2bf(xv[i].z); t[i * 4 + 3] = f2bf(xv[i].w);
            }
            *(uint4*)(xs + spos * 136 + sseg * 16)     = ((const uint4*)t)[0];
            *(uint4*)(xs + spos * 136 + sseg * 16 + 8) = ((const uint4*)t)[1];
        }
    }

    // final tile store
    __syncthreads();
    const long plast = p0 + 96;
    #pragma unroll
    for (int i = 0; i < 2; ++i) {
        const int idx = tid + i * 256;
        const int r = idx >> 4, c = idx & 15;
        *(uint4*)(attn_out + (plast + r) * DMODEL + c * 8) =
            *(const uint4*)(os + r * 136 + c * 8);
    }
}

// ---------------------------------------------------------------------------
// Kernel 2: final GEMM partials via bf16 MFMA.
//   C(1024x128) = Aflat(1024x8192 bf16) @ W(8192x128)
// ---------------------------------------------------------------------------
__global__ __launch_bounds__(256, 2) void k_fgemm_mfma(
    const unsigned short* __restrict__ attnBf,   // [1024][8192] bf16 (flat view)
    const unsigned short* __restrict__ WtBf,     // [128][8192] bf16
    float* __restrict__ P)                       // [16][1024][128] f32 partials
{
    __shared__ unsigned short As[64][136];
    __shared__ unsigned short Ws[128][136];

    const int tid   = threadIdx.x;
    const int mtile = blockIdx.x >> 4;
    const int kc    = blockIdx.x & 15;
    const int lane  = tid & 63;
    const int wave  = tid >> 6;
    const int l16   = lane & 15;
    const int lhi   = lane >> 4;

    f32x4 acc[4][2];
    #pragma unroll
    for (int mf = 0; mf < 4; ++mf)
        #pragma unroll
        for (int nt = 0; nt < 2; ++nt) acc[mf][nt] = (f32x4){0.f, 0.f, 0.f, 0.f};

    for (int st = 0; st < 4; ++st) {
        const int k0 = kc * 512 + st * 128;
        __syncthreads();
        #pragma unroll
        for (int i = 0; i < 4; ++i) {
            const int c = tid + i * 256;
            const int m = c >> 4, k8 = c & 15;
            const uint4 v = *(const uint4*)(attnBf + (long)(mtile * 64 + m) * SLEN + k0 + k8 * 8);
            *(uint4*)(&As[m][k8 * 8]) = v;
        }
        #pragma unroll
        for (int i = 0; i < 8; ++i) {
            const int c = tid + i * 256;
            const int n = c >> 4, k8 = c & 15;
            const uint4 v = *(const uint4*)(WtBf + (long)n * SLEN + k0 + k8 * 8);
            *(uint4*)(&Ws[n][k8 * 8]) = v;
        }
        __syncthreads();

        #pragma unroll
        for (int ks = 0; ks < 4; ++ks) {
            const int kk = ks * 32 + lhi * 8;
            bf16x8 af[4], bfr[2];
            #pragma unroll
            for (int mf = 0; mf < 4; ++mf)
                af[mf] = __builtin_bit_cast(bf16x8, *(const uint4*)(&As[mf * 16 + l16][kk]));
            #pragma unroll
            for (int nt = 0; nt < 2; ++nt)
                bfr[nt] = __builtin_bit_cast(bf16x8, *(const uint4*)(&Ws[(wave * 2 + nt) * 16 + l16][kk]));
            #pragma unroll
            for (int mf = 0; mf < 4; ++mf)
                #pragma unroll
                for (int nt = 0; nt < 2; ++nt)
                    acc[mf][nt] = __builtin_amdgcn_mfma_f32_16x16x32_bf16(af[mf], bfr[nt], acc[mf][nt], 0, 0, 0);
        }
    }

    float* Pp = P + ((long)kc * 1024 + mtile * 64) * 128;
    #pragma unroll
    for (int mf = 0; mf < 4; ++mf) {
        #pragma unroll
        for (int nt = 0; nt < 2; ++nt) {
            const int n = (wave * 2 + nt) * 16 + l16;
            #pragma unroll
            for (int r = 0; r < 4; ++r) {
                const int m = mf * 16 + lhi * 4 + r;
                Pp[m * 128 + n] = acc[mf][nt][r];
            }
        }
    }
}

// ---------------------------------------------------------------------------
// Kernel 3: reduce 16 K-chunk partials + bias -> out (also clears poison).
// ---------------------------------------------------------------------------
__global__ __launch_bounds__(256) void k_reduce(
    const float* __restrict__ P, const float* __restrict__ bout,
    float* __restrict__ out)
{
    const int idx = blockIdx.x * 256 + threadIdx.x;
    float v = bout[idx & 127];
    #pragma unroll
    for (int kcc = 0; kcc < 16; ++kcc) v += P[(long)kcc * 131072 + idx];
    out[idx] = v;
}

// ---------------------------------------------------------------------------
extern "C" void kernel_launch(void* const* d_in, const int* in_sizes, int n_in,
                              void* d_out, int out_size, void* d_ws, size_t ws_size,
                              hipStream_t stream)
{
    const float* x    = (const float*)d_in[0];
    const float* Wqkv = (const float*)d_in[1];
    const float* bqkv = (const float*)d_in[2];
    const float* Wout = (const float*)d_in[3];
    const float* bout = (const float*)d_in[4];
    float* out = (float*)d_out;

    // ws: [0,16MB) attn bf16 | [16,18) Wt bf16 | [18,26) P f32 | [26MB..) wfb
    unsigned short* attnBf = (unsigned short*)d_ws;
    unsigned short* WtBf   = (unsigned short*)((char*)d_ws + (16u << 20));
    float*          P      = (float*)((char*)d_ws + (18u << 20));
    unsigned short* wfb    = (unsigned short*)((char*)d_ws + (26u << 20));

    k_conv_wqkv<<<24, 256, 0, stream>>>(Wqkv, wfb);
    k_conv_wout<<<64, 256, 0, stream>>>(Wout, WtBf);
    k_qkv_attn_mfma<<<512, 256, 0, stream>>>(x, wfb, bqkv, attnBf);
    k_fgemm_mfma<<<256, 256, 0, stream>>>(attnBf, WtBf, P);
    k_reduce<<<(BATCH * DMODEL * DMODEL) / 256, 256, 0, stream>>>(P, bout, out);
}

// Round 5
// 54.737 us; speedup vs baseline: 1.2677x; 1.2677x over previous
//
#include <hip/hip_runtime.h>
#include <math.h>

#define NHEADS 4
#define HDIM   32
#define DMODEL 128
#define SLEN   8192
#define BATCH  8
#define QKVC   384   // 3 * NHEADS * HDIM

typedef __bf16 bf16x8 __attribute__((ext_vector_type(8)));
typedef float  f32x4  __attribute__((ext_vector_type(4)));

// round-to-nearest-even f32 -> bf16 bits
static __device__ __forceinline__ unsigned short f2bf(float f) {
    union { float f; unsigned int u; } v; v.f = f;
    unsigned int r = (v.u + 0x7FFFu + ((v.u >> 16) & 1u)) >> 16;
    return (unsigned short)r;
}
static __device__ __forceinline__ unsigned int pack2(float a, float b) {
    return (unsigned int)f2bf(a) | ((unsigned int)f2bf(b) << 16);
}
static __device__ __forceinline__ float bf_lo(unsigned int u) {
    union { unsigned int u; float f; } v; v.u = u << 16; return v.f;
}
static __device__ __forceinline__ float bf_hi(unsigned int u) {
    union { unsigned int u; float f; } v; v.u = u & 0xffff0000u; return v.f;
}

// ---------------------------------------------------------------------------
// Kernel W1: precompute W_qkv MFMA A-fragments (bf16) in fragment order.
// ---------------------------------------------------------------------------
__global__ __launch_bounds__(256) void k_conv_wqkv(
    const float* __restrict__ Wqkv, unsigned short* __restrict__ wfb)
{
    const int idx  = blockIdx.x * 256 + threadIdx.x;   // 0..6143
    const int lane = idx & 63;
    const int ks   = (idx >> 6) & 3;
    const int rest = idx >> 8;                         // 0..23
    const int j    = rest % 6;
    const int w    = rest / 6;
    const int ch   = w * 96 + j * 16 + (lane & 15);
    const int kb   = ks * 32 + (lane >> 4) * 8;
    unsigned short t[8];
    #pragma unroll
    for (int e = 0; e < 8; ++e) t[e] = f2bf(Wqkv[(kb + e) * QKVC + ch]);
    *(uint4*)(wfb + (long)idx * 8) = *(const uint4*)t;
}

// ---------------------------------------------------------------------------
// Kernel W2: convert + transpose W_out (f32 [8192][128]) -> Wt bf16 [128][8192]
// ---------------------------------------------------------------------------
__global__ __launch_bounds__(256) void k_conv_wout(
    const float* __restrict__ Wout, unsigned short* __restrict__ Wt)
{
    __shared__ unsigned short ts[128][136];
    const int tid = threadIdx.x;
    const int kb  = blockIdx.x;
    const float* src = Wout + (long)kb * 128 * 128;

    #pragma unroll
    for (int i = 0; i < 64; ++i) {
        const int idx = tid + i * 256;
        const int kk = idx >> 7, n = idx & 127;
        ts[n][kk] = f2bf(src[idx]);
    }
    __syncthreads();
    #pragma unroll
    for (int i = 0; i < 64; ++i) {
        const int idx = tid + i * 256;
        const int n = idx >> 7, kk = idx & 127;
        Wt[(long)n * SLEN + kb * 128 + kk] = ts[n][kk];
    }
}

// ---------------------------------------------------------------------------
// Kernel 1: fused QKV projection + per-position head-mixing attention.
// 512 blocks x 256 thr; 4 iters x 32 positions per block.
// MFMA computes qkv^T (W A-operand -> lanes own 4 consecutive channels).
// Phase split per iter:  [all] store os(it-1) + MFMA + packed qsm writes
//                        barrier
//                        [waves 0-1] softmax epilogue  ||  [waves 2-3] stage
//                        xs(it+1)   -- phase-local live ranges, no spills.
// ---------------------------------------------------------------------------
__global__ __launch_bounds__(256, 1) void k_qkv_attn_mfma(
    const float* __restrict__ x,
    const unsigned short* __restrict__ wfb,
    const float* __restrict__ bqkv,
    unsigned short* __restrict__ attn_out)   // bf16 [65536][128]
{
    __shared__ unsigned short xs[32 * 136];   // x tile bf16
    __shared__ unsigned short qsm[32 * 384];  // qkv bf16, chunk-swizzled rows
    __shared__ unsigned short os[32 * 136];   // output staging bf16

    const int tid  = threadIdx.x;
    const int lane = tid & 63;
    const int wave = tid >> 6;
    const int l16  = lane & 15;
    const int lhi  = lane >> 4;

    // resident W fragments (coalesced uint4 loads from precomputed buffer)
    bf16x8 wf[6][4];
    #pragma unroll
    for (int j = 0; j < 6; ++j)
        #pragma unroll
        for (int ks = 0; ks < 4; ++ks)
            wf[j][ks] = __builtin_bit_cast(bf16x8,
                *(const uint4*)(wfb + ((long)(((wave * 6 + j) * 4 + ks) * 64 + lane)) * 8));
    float bq[6][4];
    #pragma unroll
    for (int j = 0; j < 6; ++j)
        #pragma unroll
        for (int r = 0; r < 4; ++r)
            bq[j][r] = bqkv[wave * 96 + j * 16 + lhi * 4 + r];

    const long p0 = (long)blockIdx.x * 128;

    // prologue: stage iter-0 x tile (all 256 threads, 16 f32 each, short-lived)
    {
        const int spos = tid >> 3, sseg = tid & 7;
        const float* src = x + (p0 + spos) * DMODEL + sseg * 16;
        float4 a0 = *(const float4*)(src);
        float4 a1 = *(const float4*)(src + 4);
        float4 a2 = *(const float4*)(src + 8);
        float4 a3 = *(const float4*)(src + 12);
        unsigned short t[16] = {
            f2bf(a0.x), f2bf(a0.y), f2bf(a0.z), f2bf(a0.w),
            f2bf(a1.x), f2bf(a1.y), f2bf(a1.z), f2bf(a1.w),
            f2bf(a2.x), f2bf(a2.y), f2bf(a2.z), f2bf(a2.w),
            f2bf(a3.x), f2bf(a3.y), f2bf(a3.z), f2bf(a3.w) };
        *(uint4*)(xs + spos * 136 + sseg * 16)     = ((const uint4*)t)[0];
        *(uint4*)(xs + spos * 136 + sseg * 16 + 8) = ((const uint4*)t)[1];
    }

    for (int it = 0; it < 4; ++it) {
        __syncthreads();   // xs(it) staged; qsm free; os(it-1) complete
        const long pit = p0 + it * 32;

        // store previous iter's output (overlaps with MFMA issue)
        if (it > 0) {
            const long pprev = pit - 32;
            #pragma unroll
            for (int i = 0; i < 2; ++i) {
                const int idx = tid + i * 256;
                const int r = idx >> 4, c = idx & 15;
                *(uint4*)(attn_out + (pprev + r) * DMODEL + c * 8) =
                    *(const uint4*)(os + r * 136 + c * 8);
            }
        }

        // MFMA: qkv^T (rows = channels, cols = positions)
        {
            f32x4 acc[6][2];
            #pragma unroll
            for (int j = 0; j < 6; ++j)
                #pragma unroll
                for (int nt = 0; nt < 2; ++nt) acc[j][nt] = (f32x4){0.f, 0.f, 0.f, 0.f};

            #pragma unroll
            for (int ks = 0; ks < 4; ++ks) {
                const bf16x8 xf0 = __builtin_bit_cast(bf16x8,
                    *(const uint4*)(xs + l16 * 136 + ks * 32 + lhi * 8));
                const bf16x8 xf1 = __builtin_bit_cast(bf16x8,
                    *(const uint4*)(xs + (16 + l16) * 136 + ks * 32 + lhi * 8));
                #pragma unroll
                for (int j = 0; j < 6; ++j) {
                    acc[j][0] = __builtin_amdgcn_mfma_f32_16x16x32_bf16(wf[j][ks], xf0, acc[j][0], 0, 0, 0);
                    acc[j][1] = __builtin_amdgcn_mfma_f32_16x16x32_bf16(wf[j][ks], xf1, acc[j][1], 0, 0, 0);
                }
            }

            // acc -> qsm: packed b64 bf16 writes, chunk XOR-swizzled by p&15
            const int cb = wave * 96 + lhi * 4;
            #pragma unroll
            for (int j = 0; j < 6; ++j) {
                const int c     = cb + j * 16;
                const int chunk = c >> 3;
                const int sub   = c & 7;          // 0 or 4
                #pragma unroll
                for (int nt = 0; nt < 2; ++nt) {
                    const int p = nt * 16 + l16;  // p & 15 == l16
                    uint2 u;
                    u.x = pack2(acc[j][nt][0] + bq[j][0], acc[j][nt][1] + bq[j][1]);
                    u.y = pack2(acc[j][nt][2] + bq[j][2], acc[j][nt][3] + bq[j][3]);
                    *(uint2*)(qsm + p * 384 + (((chunk ^ l16) << 3) + sub)) = u;
                }
            }
        }
        __syncthreads();   // qsm ready; xs consumed

        if (tid < 128) {
            // ---- epilogue: thread (p = tid&31, qh = tid>>5) ----
            const int p   = tid & 31;
            const int qh  = tid >> 5;
            const int psw = p & 15;
            const unsigned short* row = qsm + p * 384;
            const float scale = 0.17677669529663687f;   // 32^-0.5

            // q: 4 chunks -> 32 f32
            float qv[32];
            #pragma unroll
            for (int c4 = 0; c4 < 4; ++c4) {
                const uint4 qc = *(const uint4*)(row + (((qh * 12 + c4) ^ psw) << 3));
                const unsigned int* w = (const unsigned int*)&qc;
                #pragma unroll
                for (int k = 0; k < 4; ++k) {
                    qv[c4 * 8 + 2 * k]     = bf_lo(w[k]);
                    qv[c4 * 8 + 2 * k + 1] = bf_hi(w[k]);
                }
            }
            // scores
            float sc[NHEADS];
            #pragma unroll
            for (int kh = 0; kh < NHEADS; ++kh) {
                float s0 = 0.f, s1 = 0.f;
                #pragma unroll
                for (int c4 = 0; c4 < 4; ++c4) {
                    const uint4 kc = *(const uint4*)(row + (((qh * 0 + kh * 12 + 4 + c4) ^ psw) << 3));
                    const unsigned int* w = (const unsigned int*)&kc;
                    #pragma unroll
                    for (int k = 0; k < 4; ++k) {
                        s0 = fmaf(bf_lo(w[k]), qv[c4 * 8 + 2 * k], s0);
                        s1 = fmaf(bf_hi(w[k]), qv[c4 * 8 + 2 * k + 1], s1);
                    }
                }
                sc[kh] = (s0 + s1) * scale;
            }
            const float m = fmaxf(fmaxf(sc[0], sc[1]), fmaxf(sc[2], sc[3]));
            float ew[NHEADS], sum = 0.f;
            #pragma unroll
            for (int kh = 0; kh < NHEADS; ++kh) { ew[kh] = __expf(sc[kh] - m); sum += ew[kh]; }
            const float inv = 1.f / sum;
            #pragma unroll
            for (int kh = 0; kh < NHEADS; ++kh) ew[kh] *= inv;

            // PV: per 8-channel chunk, accumulate over kh, store immediately
            #pragma unroll
            for (int c4 = 0; c4 < 4; ++c4) {
                float o8[8];
                #pragma unroll
                for (int e = 0; e < 8; ++e) o8[e] = 0.f;
                #pragma unroll
                for (int kh = 0; kh < NHEADS; ++kh) {
                    const uint4 vc = *(const uint4*)(row + (((kh * 12 + 8 + c4) ^ psw) << 3));
                    const unsigned int* w = (const unsigned int*)&vc;
                    const float wk = ew[kh];
                    #pragma unroll
                    for (int k = 0; k < 4; ++k) {
                        o8[2 * k]     = fmaf(wk, bf_lo(w[k]), o8[2 * k]);
                        o8[2 * k + 1] = fmaf(wk, bf_hi(w[k]), o8[2 * k + 1]);
                    }
                }
                uint4 u;
                ((unsigned int*)&u)[0] = pack2(o8[0], o8[1]);
                ((unsigned int*)&u)[1] = pack2(o8[2], o8[3]);
                ((unsigned int*)&u)[2] = pack2(o8[4], o8[5]);
                ((unsigned int*)&u)[3] = pack2(o8[6], o8[7]);
                *(uint4*)(os + p * 136 + qh * 32 + c4 * 8) = u;
            }
        } else if (it < 3) {
            // ---- waves 2,3: stage next x tile (32 f32 per thread) ----
            const int t    = tid - 128;        // 0..127
            const int srow = t >> 2;           // 0..31
            const int sseg = t & 3;            // 0..3
            const float* src = x + (pit + 32 + srow) * DMODEL + sseg * 32;
            float4 f[8];
            #pragma unroll
            for (int i = 0; i < 8; ++i) f[i] = *(const float4*)(src + i * 4);
            unsigned short tb[32];
            #pragma unroll
            for (int i = 0; i < 8; ++i) {
                tb[i * 4 + 0] = f2bf(f[i].x); tb[i * 4 + 1] = f2bf(f[i].y);
                tb[i * 4 + 2] = f2bf(f[i].z); tb[i * 4 + 3] = f2bf(f[i].w);
            }
            #pragma unroll
            for (int i = 0; i < 4; ++i)
                *(uint4*)(xs + srow * 136 + sseg * 32 + i * 8) = ((const uint4*)tb)[i];
        }
    }

    // final tile store
    __syncthreads();
    const long plast = p0 + 96;
    #pragma unroll
    for (int i = 0; i < 2; ++i) {
        const int idx = tid + i * 256;
        const int r = idx >> 4, c = idx & 15;
        *(uint4*)(attn_out + (plast + r) * DMODEL + c * 8) =
            *(const uint4*)(os + r * 136 + c * 8);
    }
}

// ---------------------------------------------------------------------------
// Kernel 2: final GEMM partials via bf16 MFMA.
//   C(1024x128) = Aflat(1024x8192 bf16) @ W(8192x128)
// ---------------------------------------------------------------------------
__global__ __launch_bounds__(256, 2) void k_fgemm_mfma(
    const unsigned short* __restrict__ attnBf,   // [1024][8192] bf16 (flat view)
    const unsigned short* __restrict__ WtBf,     // [128][8192] bf16
    float* __restrict__ P)                       // [16][1024][128] f32 partials
{
    __shared__ unsigned short As[64][136];
    __shared__ unsigned short Ws[128][136];

    const int tid   = threadIdx.x;
    const int mtile = blockIdx.x >> 4;
    const int kc    = blockIdx.x & 15;
    const int lane  = tid & 63;
    const int wave  = tid >> 6;
    const int l16   = lane & 15;
    const int lhi   = lane >> 4;

    f32x4 acc[4][2];
    #pragma unroll
    for (int mf = 0; mf < 4; ++mf)
        #pragma unroll
        for (int nt = 0; nt < 2; ++nt) acc[mf][nt] = (f32x4){0.f, 0.f, 0.f, 0.f};

    for (int st = 0; st < 4; ++st) {
        const int k0 = kc * 512 + st * 128;
        __syncthreads();
        #pragma unroll
        for (int i = 0; i < 4; ++i) {
            const int c = tid + i * 256;
            const int m = c >> 4, k8 = c & 15;
            const uint4 v = *(const uint4*)(attnBf + (long)(mtile * 64 + m) * SLEN + k0 + k8 * 8);
            *(uint4*)(&As[m][k8 * 8]) = v;
        }
        #pragma unroll
        for (int i = 0; i < 8; ++i) {
            const int c = tid + i * 256;
            const int n = c >> 4, k8 = c & 15;
            const uint4 v = *(const uint4*)(WtBf + (long)n * SLEN + k0 + k8 * 8);
            *(uint4*)(&Ws[n][k8 * 8]) = v;
        }
        __syncthreads();

        #pragma unroll
        for (int ks = 0; ks < 4; ++ks) {
            const int kk = ks * 32 + lhi * 8;
            bf16x8 af[4], bfr[2];
            #pragma unroll
            for (int mf = 0; mf < 4; ++mf)
                af[mf] = __builtin_bit_cast(bf16x8, *(const uint4*)(&As[mf * 16 + l16][kk]));
            #pragma unroll
            for (int nt = 0; nt < 2; ++nt)
                bfr[nt] = __builtin_bit_cast(bf16x8, *(const uint4*)(&Ws[(wave * 2 + nt) * 16 + l16][kk]));
            #pragma unroll
            for (int mf = 0; mf < 4; ++mf)
                #pragma unroll
                for (int nt = 0; nt < 2; ++nt)
                    acc[mf][nt] = __builtin_amdgcn_mfma_f32_16x16x32_bf16(af[mf], bfr[nt], acc[mf][nt], 0, 0, 0);
        }
    }

    float* Pp = P + ((long)kc * 1024 + mtile * 64) * 128;
    #pragma unroll
    for (int mf = 0; mf < 4; ++mf) {
        #pragma unroll
        for (int nt = 0; nt < 2; ++nt) {
            const int n = (wave * 2 + nt) * 16 + l16;
            #pragma unroll
            for (int r = 0; r < 4; ++r) {
                const int m = mf * 16 + lhi * 4 + r;
                Pp[m * 128 + n] = acc[mf][nt][r];
            }
        }
    }
}

// ---------------------------------------------------------------------------
// Kernel 3: reduce 16 K-chunk partials + bias -> out (also clears poison).
// ---------------------------------------------------------------------------
__global__ __launch_bounds__(256) void k_reduce(
    const float* __restrict__ P, const float* __restrict__ bout,
    float* __restrict__ out)
{
    const int idx = blockIdx.x * 256 + threadIdx.x;
    float v = bout[idx & 127];
    #pragma unroll
    for (int kcc = 0; kcc < 16; ++kcc) v += P[(long)kcc * 131072 + idx];
    out[idx] = v;
}

// ---------------------------------------------------------------------------
extern "C" void kernel_launch(void* const* d_in, const int* in_sizes, int n_in,
                              void* d_out, int out_size, void* d_ws, size_t ws_size,
                              hipStream_t stream)
{
    const float* x    = (const float*)d_in[0];
    const float* Wqkv = (const float*)d_in[1];
    const float* bqkv = (const float*)d_in[2];
    const float* Wout = (const float*)d_in[3];
    const float* bout = (const float*)d_in[4];
    float* out = (float*)d_out;

    // ws: [0,16MB) attn bf16 | [16,18) Wt bf16 | [18,26) P f32 | [26MB..) wfb
    unsigned short* attnBf = (unsigned short*)d_ws;
    unsigned short* WtBf   = (unsigned short*)((char*)d_ws + (16u << 20));
    float*          P      = (float*)((char*)d_ws + (18u << 20));
    unsigned short* wfb    = (unsigned short*)((char*)d_ws + (26u << 20));

    k_conv_wqkv<<<24, 256, 0, stream>>>(Wqkv, wfb);
    k_conv_wout<<<64, 256, 0, stream>>>(Wout, WtBf);
    k_qkv_attn_mfma<<<512, 256, 0, stream>>>(x, wfb, bqkv, attnBf);
    k_fgemm_mfma<<<256, 256, 0, stream>>>(attnBf, WtBf, P);
    k_reduce<<<(BATCH * DMODEL * DMODEL) / 256, 256, 0, stream>>>(P, bout, out);
}

// Round 6
// 46.444 us; speedup vs baseline: 1.4941x; 1.1786x over previous
//
#include <hip/hip_runtime.h>
#include <math.h>

#define NHEADS 4
#define HDIM   32
#define DMODEL 128
#define SLEN   8192
#define BATCH  8
#define QKVC   384   // 3 * NHEADS * HDIM

typedef __bf16 bf16x8 __attribute__((ext_vector_type(8)));
typedef float  f32x4  __attribute__((ext_vector_type(4)));

// round-to-nearest-even f32 -> bf16 bits (host-side-equivalent, used in W prep)
static __device__ __forceinline__ unsigned short f2bf(float f) {
    union { float f; unsigned int u; } v; v.f = f;
    unsigned int r = (v.u + 0x7FFFu + ((v.u >> 16) & 1u)) >> 16;
    return (unsigned short)r;
}
// hardware cvt pack (compiler emits v_cvt_pk_bf16_f32)
static __device__ __forceinline__ unsigned int pk2(float a, float b) {
    unsigned short ua = __builtin_bit_cast(unsigned short, (__bf16)a);
    unsigned short ub = __builtin_bit_cast(unsigned short, (__bf16)b);
    return (unsigned int)ua | ((unsigned int)ub << 16);
}
static __device__ __forceinline__ float bf_lo(unsigned int u) {
    union { unsigned int u; float f; } v; v.u = u << 16; return v.f;
}
static __device__ __forceinline__ float bf_hi(unsigned int u) {
    union { unsigned int u; float f; } v; v.u = u & 0xffff0000u; return v.f;
}

// ---------------------------------------------------------------------------
// Kernel W1: precompute W_qkv MFMA A-fragments (bf16) in fragment order.
//   wfb[(((wave*6+j)*4+ks)*64+lane)*8 + e]
// ---------------------------------------------------------------------------
__global__ __launch_bounds__(256) void k_conv_wqkv(
    const float* __restrict__ Wqkv, unsigned short* __restrict__ wfb)
{
    const int idx  = blockIdx.x * 256 + threadIdx.x;   // 0..6143
    const int lane = idx & 63;
    const int ks   = (idx >> 6) & 3;
    const int rest = idx >> 8;                         // 0..23
    const int j    = rest % 6;
    const int w    = rest / 6;
    const int ch   = w * 96 + j * 16 + (lane & 15);
    const int kb   = ks * 32 + (lane >> 4) * 8;
    unsigned short t[8];
    #pragma unroll
    for (int e = 0; e < 8; ++e) t[e] = f2bf(Wqkv[(kb + e) * QKVC + ch]);
    *(uint4*)(wfb + (long)idx * 8) = *(const uint4*)t;
}

// ---------------------------------------------------------------------------
// Kernel W2: convert + transpose W_out (f32 [8192][128]) -> Wt bf16 [128][8192]
// ---------------------------------------------------------------------------
__global__ __launch_bounds__(256) void k_conv_wout(
    const float* __restrict__ Wout, unsigned short* __restrict__ Wt)
{
    __shared__ unsigned short ts[128][136];
    const int tid = threadIdx.x;
    const int kb  = blockIdx.x;
    const float* src = Wout + (long)kb * 128 * 128;

    #pragma unroll
    for (int i = 0; i < 64; ++i) {
        const int idx = tid + i * 256;
        const int kk = idx >> 7, n = idx & 127;
        ts[n][kk] = f2bf(src[idx]);
    }
    __syncthreads();
    #pragma unroll
    for (int i = 0; i < 64; ++i) {
        const int idx = tid + i * 256;
        const int n = idx >> 7, kk = idx & 127;
        Wt[(long)n * SLEN + kb * 128 + kk] = ts[n][kk];
    }
}

// ---------------------------------------------------------------------------
// Kernel 1: fused QKV projection + per-position head-mixing attention.
// 2048 blocks x 256 thr; ONE 32-position tile per block (max parallelism,
// 2 barriers total). MFMA computes qkv^T (W A-operand; lane owns 4 consecutive
// channels -> packed b64 writes into XOR-swizzled qsm). W fragments loaded
// per-k-slice from L2-hot wfb (no resident 96-VGPR array).
// Epilogue: 256 threads = (p, qh, half); 16-d score partial + shfl_xor(1);
// softmax; 16-channel PV; direct coalesced global store.
// ---------------------------------------------------------------------------
__global__ __launch_bounds__(256, 3) void k_qkv_attn_mfma(
    const float* __restrict__ x,
    const unsigned short* __restrict__ wfb,
    const float* __restrict__ bqkv,
    unsigned short* __restrict__ attn_out)   // bf16 [65536][128]
{
    __shared__ unsigned short xs[32 * 136];   // x tile bf16
    __shared__ unsigned short qsm[32 * 384];  // qkv bf16, chunk-swizzled rows

    const int tid  = threadIdx.x;
    const int lane = tid & 63;
    const int wave = tid >> 6;
    const int l16  = lane & 15;
    const int lhi  = lane >> 4;
    const long p0  = (long)blockIdx.x * 32;

    // ---- stage x tile: 16 f32 per thread, hw cvt to bf16 ----
    {
        const int spos = tid >> 3, sseg = tid & 7;
        const float* src = x + (p0 + spos) * DMODEL + sseg * 16;
        float4 a0 = *(const float4*)(src);
        float4 a1 = *(const float4*)(src + 4);
        float4 a2 = *(const float4*)(src + 8);
        float4 a3 = *(const float4*)(src + 12);
        unsigned int t[8] = {
            pk2(a0.x, a0.y), pk2(a0.z, a0.w), pk2(a1.x, a1.y), pk2(a1.z, a1.w),
            pk2(a2.x, a2.y), pk2(a2.z, a2.w), pk2(a3.x, a3.y), pk2(a3.z, a3.w) };
        *(uint4*)(xs + spos * 136 + sseg * 16)     = ((const uint4*)t)[0];
        *(uint4*)(xs + spos * 136 + sseg * 16 + 8) = ((const uint4*)t)[1];
    }
    __syncthreads();

    // ---- MFMA: qkv^T (rows = channels, cols = positions) ----
    {
        f32x4 acc[6][2];
        #pragma unroll
        for (int j = 0; j < 6; ++j)
            #pragma unroll
            for (int nt = 0; nt < 2; ++nt) acc[j][nt] = (f32x4){0.f, 0.f, 0.f, 0.f};

        const unsigned short* wbase = wfb + ((long)(wave * 24) * 64 + lane) * 8;

        #pragma unroll
        for (int ks = 0; ks < 4; ++ks) {
            const bf16x8 xf0 = __builtin_bit_cast(bf16x8,
                *(const uint4*)(xs + l16 * 136 + ks * 32 + lhi * 8));
            const bf16x8 xf1 = __builtin_bit_cast(bf16x8,
                *(const uint4*)(xs + (16 + l16) * 136 + ks * 32 + lhi * 8));
            #pragma unroll
            for (int j = 0; j < 6; ++j) {
                const bf16x8 wj = __builtin_bit_cast(bf16x8,
                    *(const uint4*)(wbase + (j * 4 + ks) * 512));
                acc[j][0] = __builtin_amdgcn_mfma_f32_16x16x32_bf16(wj, xf0, acc[j][0], 0, 0, 0);
                acc[j][1] = __builtin_amdgcn_mfma_f32_16x16x32_bf16(wj, xf1, acc[j][1], 0, 0, 0);
            }
        }

        // acc (+bias) -> qsm: packed b64 bf16 writes, chunk XOR-swizzled
        #pragma unroll
        for (int j = 0; j < 6; ++j) {
            const float4 bb = *(const float4*)(bqkv + wave * 96 + j * 16 + lhi * 4);
            const int c     = wave * 96 + lhi * 4 + j * 16;
            const int chunk = c >> 3;
            const int sub   = c & 7;          // 0 or 4
            #pragma unroll
            for (int nt = 0; nt < 2; ++nt) {
                const int p = nt * 16 + l16;  // p & 15 == l16
                uint2 u;
                u.x = pk2(acc[j][nt][0] + bb.x, acc[j][nt][1] + bb.y);
                u.y = pk2(acc[j][nt][2] + bb.z, acc[j][nt][3] + bb.w);
                *(uint2*)(qsm + p * 384 + (((chunk ^ l16) << 3) + sub)) = u;
            }
        }
    }
    __syncthreads();

    // ---- epilogue: thread = (p = tid>>3, qh = (tid>>1)&3, h = tid&1) ----
    {
        const int p   = tid >> 3;
        const int qh  = (tid >> 1) & 3;
        const int h   = tid & 1;
        const int psw = p & 15;
        const unsigned short* row = qsm + p * 384;
        const float scale = 0.17677669529663687f;   // 32^-0.5

        // q half: 2 chunks -> 16 f32
        float qf[16];
        {
            const int qc = qh * 12 + h * 2;
            #pragma unroll
            for (int cc = 0; cc < 2; ++cc) {
                const uint4 qv = *(const uint4*)(row + (((qc + cc) ^ psw) << 3));
                const unsigned int* w = (const unsigned int*)&qv;
                #pragma unroll
                for (int k = 0; k < 4; ++k) {
                    qf[cc * 8 + 2 * k]     = bf_lo(w[k]);
                    qf[cc * 8 + 2 * k + 1] = bf_hi(w[k]);
                }
            }
        }
        // scores: 16-d partial per thread, completed via shfl_xor(1)
        float sc[NHEADS];
        #pragma unroll
        for (int kh = 0; kh < NHEADS; ++kh) {
            float s = 0.f;
            const int kc = kh * 12 + 4 + h * 2;
            #pragma unroll
            for (int cc = 0; cc < 2; ++cc) {
                const uint4 kv = *(const uint4*)(row + (((kc + cc) ^ psw) << 3));
                const unsigned int* w = (const unsigned int*)&kv;
                #pragma unroll
                for (int k = 0; k < 4; ++k) {
                    s = fmaf(bf_lo(w[k]), qf[cc * 8 + 2 * k], s);
                    s = fmaf(bf_hi(w[k]), qf[cc * 8 + 2 * k + 1], s);
                }
            }
            sc[kh] = (s + __shfl_xor(s, 1)) * scale;
        }
        const float m = fmaxf(fmaxf(sc[0], sc[1]), fmaxf(sc[2], sc[3]));
        float ew[NHEADS], sum = 0.f;
        #pragma unroll
        for (int kh = 0; kh < NHEADS; ++kh) { ew[kh] = __expf(sc[kh] - m); sum += ew[kh]; }
        const float inv = 1.f / sum;
        #pragma unroll
        for (int kh = 0; kh < NHEADS; ++kh) ew[kh] *= inv;

        // PV: 16 output channels (d = h*16 .. h*16+16)
        float o[16];
        #pragma unroll
        for (int e = 0; e < 16; ++e) o[e] = 0.f;
        #pragma unroll
        for (int kh = 0; kh < NHEADS; ++kh) {
            const float wk = ew[kh];
            const int vc = kh * 12 + 8 + h * 2;
            #pragma unroll
            for (int cc = 0; cc < 2; ++cc) {
                const uint4 vv = *(const uint4*)(row + (((vc + cc) ^ psw) << 3));
                const unsigned int* w = (const unsigned int*)&vv;
                #pragma unroll
                for (int k = 0; k < 4; ++k) {
                    o[cc * 8 + 2 * k]     = fmaf(wk, bf_lo(w[k]), o[cc * 8 + 2 * k]);
                    o[cc * 8 + 2 * k + 1] = fmaf(wk, bf_hi(w[k]), o[cc * 8 + 2 * k + 1]);
                }
            }
        }
        // pack + direct global store (32 B per thread, wave-contiguous)
        unsigned int ow[8];
        #pragma unroll
        for (int e = 0; e < 8; ++e) ow[e] = pk2(o[2 * e], o[2 * e + 1]);
        unsigned short* dst = attn_out + (p0 + p) * DMODEL + qh * 32 + h * 16;
        *(uint4*)(dst)     = ((const uint4*)ow)[0];
        *(uint4*)(dst + 8) = ((const uint4*)ow)[1];
    }
}

// ---------------------------------------------------------------------------
// Kernel 2: final GEMM partials via bf16 MFMA.
//   C(1024x128) = Aflat(1024x8192 bf16) @ W(8192x128)
// ---------------------------------------------------------------------------
__global__ __launch_bounds__(256, 2) void k_fgemm_mfma(
    const unsigned short* __restrict__ attnBf,   // [1024][8192] bf16 (flat view)
    const unsigned short* __restrict__ WtBf,     // [128][8192] bf16
    float* __restrict__ P)                       // [16][1024][128] f32 partials
{
    __shared__ unsigned short As[64][136];
    __shared__ unsigned short Ws[128][136];

    const int tid   = threadIdx.x;
    const int mtile = blockIdx.x >> 4;
    const int kc    = blockIdx.x & 15;
    const int lane  = tid & 63;
    const int wave  = tid >> 6;
    const int l16   = lane & 15;
    const int lhi   = lane >> 4;

    f32x4 acc[4][2];
    #pragma unroll
    for (int mf = 0; mf < 4; ++mf)
        #pragma unroll
        for (int nt = 0; nt < 2; ++nt) acc[mf][nt] = (f32x4){0.f, 0.f, 0.f, 0.f};

    for (int st = 0; st < 4; ++st) {
        const int k0 = kc * 512 + st * 128;
        __syncthreads();
        #pragma unroll
        for (int i = 0; i < 4; ++i) {
            const int c = tid + i * 256;
            const int m = c >> 4, k8 = c & 15;
            const uint4 v = *(const uint4*)(attnBf + (long)(mtile * 64 + m) * SLEN + k0 + k8 * 8);
            *(uint4*)(&As[m][k8 * 8]) = v;
        }
        #pragma unroll
        for (int i = 0; i < 8; ++i) {
            const int c = tid + i * 256;
            const int n = c >> 4, k8 = c & 15;
            const uint4 v = *(const uint4*)(WtBf + (long)n * SLEN + k0 + k8 * 8);
            *(uint4*)(&Ws[n][k8 * 8]) = v;
        }
        __syncthreads();

        #pragma unroll
        for (int ks = 0; ks < 4; ++ks) {
            const int kk = ks * 32 + lhi * 8;
            bf16x8 af[4], bfr[2];
            #pragma unroll
            for (int mf = 0; mf < 4; ++mf)
                af[mf] = __builtin_bit_cast(bf16x8, *(const uint4*)(&As[mf * 16 + l16][kk]));
            #pragma unroll
            for (int nt = 0; nt < 2; ++nt)
                bfr[nt] = __builtin_bit_cast(bf16x8, *(const uint4*)(&Ws[(wave * 2 + nt) * 16 + l16][kk]));
            #pragma unroll
            for (int mf = 0; mf < 4; ++mf)
                #pragma unroll
                for (int nt = 0; nt < 2; ++nt)
                    acc[mf][nt] = __builtin_amdgcn_mfma_f32_16x16x32_bf16(af[mf], bfr[nt], acc[mf][nt], 0, 0, 0);
        }
    }

    float* Pp = P + ((long)kc * 1024 + mtile * 64) * 128;
    #pragma unroll
    for (int mf = 0; mf < 4; ++mf) {
        #pragma unroll
        for (int nt = 0; nt < 2; ++nt) {
            const int n = (wave * 2 + nt) * 16 + l16;
            #pragma unroll
            for (int r = 0; r < 4; ++r) {
                const int m = mf * 16 + lhi * 4 + r;
                Pp[m * 128 + n] = acc[mf][nt][r];
            }
        }
    }
}

// ---------------------------------------------------------------------------
// Kernel 3: reduce 16 K-chunk partials + bias -> out (also clears poison).
// ---------------------------------------------------------------------------
__global__ __launch_bounds__(256) void k_reduce(
    const float* __restrict__ P, const float* __restrict__ bout,
    float* __restrict__ out)
{
    const int idx = blockIdx.x * 256 + threadIdx.x;
    float v = bout[idx & 127];
    #pragma unroll
    for (int kcc = 0; kcc < 16; ++kcc) v += P[(long)kcc * 131072 + idx];
    out[idx] = v;
}

// ---------------------------------------------------------------------------
extern "C" void kernel_launch(void* const* d_in, const int* in_sizes, int n_in,
                              void* d_out, int out_size, void* d_ws, size_t ws_size,
                              hipStream_t stream)
{
    const float* x    = (const float*)d_in[0];
    const float* Wqkv = (const float*)d_in[1];
    const float* bqkv = (const float*)d_in[2];
    const float* Wout = (const float*)d_in[3];
    const float* bout = (const float*)d_in[4];
    float* out = (float*)d_out;

    // ws: [0,16MB) attn bf16 | [16,18) Wt bf16 | [18,26) P f32 | [26MB..) wfb
    unsigned short* attnBf = (unsigned short*)d_ws;
    unsigned short* WtBf   = (unsigned short*)((char*)d_ws + (16u << 20));
    float*          P      = (float*)((char*)d_ws + (18u << 20));
    unsigned short* wfb    = (unsigned short*)((char*)d_ws + (26u << 20));

    k_conv_wqkv<<<24, 256, 0, stream>>>(Wqkv, wfb);
    k_conv_wout<<<64, 256, 0, stream>>>(Wout, WtBf);
    k_qkv_attn_mfma<<<2048, 256, 0, stream>>>(x, wfb, bqkv, attnBf);
    k_fgemm_mfma<<<256, 256, 0, stream>>>(attnBf, WtBf, P);
    k_reduce<<<(BATCH * DMODEL * DMODEL) / 256, 256, 0, stream>>>(P, bout, out);
}